// Round 11
// baseline (395.238 us; speedup 1.0000x reference)
//
#include <hip/hip_runtime.h>
#include <hip/hip_bf16.h>

typedef __hip_bfloat16 bf16;
typedef __attribute__((ext_vector_type(8))) short short8v;
typedef __attribute__((ext_vector_type(4))) float float4v;

#define NNODES 169
#define NNTOT  338
#define CH     256
#define NH     4
#define NL     3
#define SPAD   176
#define TPAD   177
#define M1PAD  536
#define LN_EPS 1e-5f

__device__ __forceinline__ float b2f(bf16 v) { return __bfloat162float(v); }
__device__ __forceinline__ float lrelu(float v) { return fmaxf(v, 0.2f * v); }
__device__ __forceinline__ float ldm(const void* p, size_t i, int isbf) {
    return isbf ? b2f(((const bf16*)p)[i]) : ((const float*)p)[i];
}
__device__ __forceinline__ short f2bf(float f) {   // RNE fp32 -> bf16 bits
    union { float f; unsigned u; } x; x.f = f;
    return (short)((x.u + 0x7FFFu + ((x.u >> 16) & 1u)) >> 16);
}
__device__ __forceinline__ int sniff_bf(const void* lng) {
    return ((((const unsigned*)lng)[0] & 0xFFFFu) == 0x3F80u) ? 1 : 0;
}

// ---------------------------------------------------------------- weight transpose
// WT[n][k] bf16 for all 4 weight families x 3 layers. grid (256,1,12).
__global__ __launch_bounds__(256) void k_wt(
    const void* __restrict__ Wl, const void* __restrict__ Wr,
    const void* __restrict__ W1, const void* __restrict__ W2,
    short* __restrict__ wlT, short* __restrict__ wrT,
    short* __restrict__ w1T, short* __restrict__ w2T,
    const void* __restrict__ lng)
{
    __shared__ float s_t[32][33];
    const int isbf = sniff_bf(lng);
    const int z = blockIdx.z, mat = z & 3, l = z >> 2;
    const void* src; short* dst; int K, N;
    if      (mat == 0) { src = Wl; dst = wlT; K = CH;     N = NH * CH; }
    else if (mat == 1) { src = Wr; dst = wrT; K = CH;     N = NH * CH; }
    else if (mat == 2) { src = W1; dst = w1T; K = CH;     N = 2 * CH;  }
    else               { src = W2; dst = w2T; K = 2 * CH; N = CH;      }
    const int tiles = (K >> 5) * (N >> 5);
    if ((int)blockIdx.x >= tiles) return;
    const int tn = blockIdx.x % (N >> 5), tk = blockIdx.x / (N >> 5);
    const int k0 = tk * 32, n0 = tn * 32;
    const size_t lKN = (size_t)l * K * N;
    const int tx = threadIdx.x & 31, ty = threadIdx.x >> 5;

    for (int r = ty; r < 32; r += 8)
        s_t[r][tx] = ldm(src, lKN + (size_t)(k0 + r) * N + n0 + tx, isbf);
    __syncthreads();
    for (int r = ty; r < 32; r += 8)
        dst[lKN + (size_t)(n0 + r) * K + k0 + tx] = f2bf(s_t[tx][r]);
}

// ---------------------------------------------------------------- MFMA GEMM core
// 64x64 tile, full-K LDS stage (ONE barrier), then KK/32 uninterrupted MFMA
// chunks. A fp32 (or raw bf16) -> bf16 staged; WT[n][k] bf16 pre-transposed.
template<int KK, int ACT, int RES>
__device__ __forceinline__ void mfma_gemm(
    short* __restrict__ sA, short* __restrict__ sBT,
    const void* __restrict__ Av, int a_bf,
    const short* __restrict__ WT,
    const void* __restrict__ bv_, size_t oB, int isbf,
    const void* __restrict__ x_res, int r_bf,
    float* __restrict__ out,
    int M, int N, int row0, int col0)
{
    const int STR = KK + 8;                    // shorts; 2-way banks (free)
    const int tid = threadIdx.x, lane = tid & 63, w = tid >> 6;
    const int r = tid >> 2, q = tid & 3;       // stage: row, k-quarter
    const int kseg = KK / 4, kb0 = q * kseg;
    const int m = lane & 15, kb = (lane >> 4) * 8;
    const int w16 = w * 16;

    {   // ---- stage A (convert to bf16) and B, one pass
        const int gr = row0 + r;
        const int ok = (gr < M);
        if (a_bf) {
            const bf16* ap = (const bf16*)Av + (size_t)gr * KK + kb0;
            #pragma unroll
            for (int j = 0; j < kseg; j += 8) {
                int4 v = ok ? *(const int4*)(ap + j) : make_int4(0, 0, 0, 0);
                *(int4*)&sA[r * STR + kb0 + j] = v;
            }
        } else {
            const float* ap = (const float*)Av + (size_t)gr * KK + kb0;
            #pragma unroll
            for (int j = 0; j < kseg; j += 8) {
                short v8[8];
                if (ok) {
                    const float4 f0 = *(const float4*)(ap + j);
                    const float4 f1 = *(const float4*)(ap + j + 4);
                    v8[0] = f2bf(f0.x); v8[1] = f2bf(f0.y);
                    v8[2] = f2bf(f0.z); v8[3] = f2bf(f0.w);
                    v8[4] = f2bf(f1.x); v8[5] = f2bf(f1.y);
                    v8[6] = f2bf(f1.z); v8[7] = f2bf(f1.w);
                } else {
                    #pragma unroll
                    for (int u = 0; u < 8; u++) v8[u] = 0;
                }
                *(int4*)&sA[r * STR + kb0 + j] = *(int4*)v8;
            }
        }
        const short* bp = WT + (size_t)(col0 + r) * KK + kb0;
        #pragma unroll
        for (int j = 0; j < kseg; j += 8)
            *(int4*)&sBT[r * STR + kb0 + j] = *(const int4*)(bp + j);
    }
    __syncthreads();

    float4v acc[4];
    #pragma unroll
    for (int t = 0; t < 4; t++) acc[t] = (float4v){0.f, 0.f, 0.f, 0.f};

    #pragma unroll
    for (int kc = 0; kc < KK / 32; kc++) {
        const short8v af = *(const short8v*)&sA[(w16 + m) * STR + kc * 32 + kb];
        #pragma unroll
        for (int t = 0; t < 4; t++) {
            const short8v bfv = *(const short8v*)&sBT[(t * 16 + m) * STR + kc * 32 + kb];
            acc[t] = __builtin_amdgcn_mfma_f32_16x16x32_bf16(af, bfv, acc[t], 0, 0, 0);
        }
    }

    const int rq = (lane >> 4) * 4;
    #pragma unroll
    for (int t = 0; t < 4; t++) {
        const int col = col0 + t * 16 + m;
        const float bias_v = ldm(bv_, oB + col, isbf);
        #pragma unroll
        for (int rr = 0; rr < 4; rr++) {
            const int gr = row0 + w16 + rq + rr;
            if (gr >= M) continue;
            float v = acc[t][rr] + bias_v;
            if (ACT) v = fmaxf(v, 0.f);
            if (RES) v += ldm(x_res, (size_t)gr * N + col, r_bf);
            out[(size_t)gr * N + col] = v;
        }
    }
}

// grid (6,16,2): z=0 -> xl, z=1 -> xr.  K=256, N=1024.
__global__ __launch_bounds__(256) void k_gemm_lr(
    const void* __restrict__ Av, int israw,
    const short* __restrict__ wlT, const short* __restrict__ wrT, size_t oWT,
    const void* __restrict__ bl, const void* __restrict__ br, size_t oB,
    float* __restrict__ xl, float* __restrict__ xr,
    const void* __restrict__ lng)
{
    __shared__ short sA[64 * 264];
    __shared__ short sBT[64 * 264];
    const int isbf = sniff_bf(lng);
    const int a_bf = israw ? isbf : 0;
    const int row0 = blockIdx.x * 64, col0 = blockIdx.y * 64;
    if (blockIdx.z == 0)
        mfma_gemm<256,0,0>(sA, sBT, Av, a_bf, wlT + oWT, bl, oB, isbf,
                           nullptr, 0, xl, NNTOT, NH * CH, row0, col0);
    else
        mfma_gemm<256,0,0>(sA, sBT, Av, a_bf, wrT + oWT, br, oB, isbf,
                           nullptr, 0, xr, NNTOT, NH * CH, row0, col0);
}

// ---------------------------------------------------------------- logits + softmax
// grid (43, NH, 2): block owns 4 targets for one (g,h). xl h-slice staged to
// LDS transposed in 4 chunks of 64ch x 176src; channel loop all-LDS; softmax
// fused. Writes alphaR rows with 0.25/z folded in.
__global__ __launch_bounds__(256) void k_logits_sm(
    const float* __restrict__ xl, const float* __restrict__ xr,
    const void* __restrict__ att, size_t oA,
    float* __restrict__ alphaR, const void* __restrict__ lng)
{
    __shared__ float s_att[CH];
    __shared__ float s_xr[4 * CH];
    __shared__ float s_tile[64 * TPAD];
    __shared__ float s_log[4 * SPAD];
    const int isbf = sniff_bf(lng);
    const int g = blockIdx.z, h = blockIdx.y, d0 = blockIdx.x * 4;
    const int tid = threadIdx.x, lane = tid & 63, wv = tid >> 6;

    s_att[tid] = ldm(att, oA + h * CH + tid, isbf);
    #pragma unroll
    for (int i = 0; i < 4; i++) {
        const int d = d0 + i;
        s_xr[i * CH + tid] = (d < NNODES)
            ? xr[(size_t)(g * NNODES + d) * (NH * CH) + h * CH + tid] : 0.f;
    }

    float l0 = 0.f, l1 = 0.f, l2 = 0.f, l3 = 0.f;
    const int s = tid;
    for (int ch = 0; ch < 4; ch++) {
        __syncthreads();
        for (int i = tid; i < SPAD * 16; i += 256) {
            const int si = i >> 4, c4 = (i & 15) * 4;
            const float4 v = (si < NNODES)
                ? *(const float4*)(xl + (size_t)(g * NNODES + si) * (NH * CH)
                                   + h * CH + ch * 64 + c4)
                : make_float4(0.f, 0.f, 0.f, 0.f);
            s_tile[(c4 + 0) * TPAD + si] = v.x;
            s_tile[(c4 + 1) * TPAD + si] = v.y;
            s_tile[(c4 + 2) * TPAD + si] = v.z;
            s_tile[(c4 + 3) * TPAD + si] = v.w;
        }
        __syncthreads();
        if (s < NNODES) {
            const int cb = ch * 64;
            #pragma unroll 8
            for (int c = 0; c < 64; c++) {
                const float v = s_tile[c * TPAD + s];
                const float a = s_att[cb + c];
                l0 += a * lrelu(v + s_xr[cb + c]);
                l1 += a * lrelu(v + s_xr[CH + cb + c]);
                l2 += a * lrelu(v + s_xr[2 * CH + cb + c]);
                l3 += a * lrelu(v + s_xr[3 * CH + cb + c]);
            }
        }
    }
    if (s < NNODES) {
        s_log[s] = l0; s_log[SPAD + s] = l1;
        s_log[2 * SPAD + s] = l2; s_log[3 * SPAD + s] = l3;
    }
    __syncthreads();

    {   // wave wv reduces target row wv
        const int d = d0 + wv;
        const float* row = s_log + wv * SPAD;
        const int s0 = lane, s1 = lane + 64, s2 = lane + 128;
        const float v0 = (s0 < NNODES && s0 != d) ? row[s0] : -1e30f;
        const float v1 = (s1 < NNODES && s1 != d) ? row[s1] : -1e30f;
        const float v2 = (s2 < NNODES && s2 != d) ? row[s2] : -1e30f;
        float mx = fmaxf(v0, fmaxf(v1, v2));
        mx = fmaxf(mx, __shfl_xor(mx, 32)); mx = fmaxf(mx, __shfl_xor(mx, 16));
        mx = fmaxf(mx, __shfl_xor(mx, 8));  mx = fmaxf(mx, __shfl_xor(mx, 4));
        mx = fmaxf(mx, __shfl_xor(mx, 2));  mx = fmaxf(mx, __shfl_xor(mx, 1));
        const float e0 = expf(v0 - mx), e1 = expf(v1 - mx), e2 = expf(v2 - mx);
        float z = e0 + e1 + e2;
        z += __shfl_xor(z, 32); z += __shfl_xor(z, 16); z += __shfl_xor(z, 8);
        z += __shfl_xor(z, 4);  z += __shfl_xor(z, 2);  z += __shfl_xor(z, 1);
        const float sc = 0.25f / (z + 1e-16f);     // head-mean folded in
        if (d < NNODES) {
            float* arow = alphaR + ((size_t)(g * NH + h) * NNODES + d) * SPAD;
            if (s0 < NNODES) arow[s0] = e0 * sc;
            if (s1 < NNODES) arow[s1] = e1 * sc;
            if (s2 < NNODES) arow[s2] = e2 * sc;
        }
    }
}

// ---------------------------------------------------------------- aggregate as GEMM
// part[h][g*169+d][c] = sum_s alpha[d,s] * xl[s, h*256+c], per (g,h).
// grid (6 d-tiles of 32, 4 c-tiles of 64, 8 gh). K = sources, BK=32.
__global__ __launch_bounds__(256) void k_agg(
    const float* __restrict__ alphaR, const float* __restrict__ xl,
    float* __restrict__ part)
{
    __shared__ float s_a[32 * 33];
    __shared__ float s_x[32 * 64];
    const int gh = blockIdx.z, g = gh >> 2, h = gh & 3;
    const int d0 = blockIdx.x * 32, c0 = blockIdx.y * 64;
    const int tid = threadIdx.x;
    const int dr = (tid >> 4) * 2, cq = (tid & 15) * 4;
    const int sr = tid >> 3, sc4 = (tid & 7) * 4;
    const int xc8 = (tid & 7) * 8;

    float acc[2][4] = {{0.f,0.f,0.f,0.f},{0.f,0.f,0.f,0.f}};

    for (int s0 = 0; s0 < NNODES; s0 += 32) {
        __syncthreads();
        {
            const int d = d0 + sr;
            const float* ap = alphaR + ((size_t)gh * NNODES + d) * SPAD + s0 + sc4;
            const int ok = (d < NNODES);
            s_a[sr * 33 + sc4 + 0] = (ok && s0 + sc4 + 0 < NNODES) ? ap[0] : 0.f;
            s_a[sr * 33 + sc4 + 1] = (ok && s0 + sc4 + 1 < NNODES) ? ap[1] : 0.f;
            s_a[sr * 33 + sc4 + 2] = (ok && s0 + sc4 + 2 < NNODES) ? ap[2] : 0.f;
            s_a[sr * 33 + sc4 + 3] = (ok && s0 + sc4 + 3 < NNODES) ? ap[3] : 0.f;
        }
        {
            const int sg = s0 + sr;
            if (sg < NNODES) {
                const float* xp = xl + (size_t)(g * NNODES + sg) * (NH * CH) + h * CH + c0 + xc8;
                *(float4*)&s_x[sr * 64 + xc8]     = *(const float4*)(xp);
                *(float4*)&s_x[sr * 64 + xc8 + 4] = *(const float4*)(xp + 4);
            } else {
                #pragma unroll
                for (int j = 0; j < 8; j++) s_x[sr * 64 + xc8 + j] = 0.f;
            }
        }
        __syncthreads();
        #pragma unroll
        for (int k = 0; k < 32; k++) {
            const float a0 = s_a[(dr + 0) * 33 + k];
            const float a1 = s_a[(dr + 1) * 33 + k];
            const float4 xv = *(const float4*)&s_x[k * 64 + cq];
            acc[0][0] += a0 * xv.x; acc[0][1] += a0 * xv.y;
            acc[0][2] += a0 * xv.z; acc[0][3] += a0 * xv.w;
            acc[1][0] += a1 * xv.x; acc[1][1] += a1 * xv.y;
            acc[1][2] += a1 * xv.z; acc[1][3] += a1 * xv.w;
        }
    }
    #pragma unroll
    for (int i = 0; i < 2; i++) {
        const int d = d0 + dr + i;
        if (d >= NNODES) continue;
        float4 v;
        v.x = acc[i][0]; v.y = acc[i][1]; v.z = acc[i][2]; v.w = acc[i][3];
        *(float4*)(part + ((size_t)h * NNTOT + g * NNODES + d) * CH + c0 + cq) = v;
    }
}

// ---------------------------------------------------------------- head-sum + LN
__global__ __launch_bounds__(256) void k_ln(
    const float* __restrict__ part,
    const void* __restrict__ bias, size_t oB,
    const void* __restrict__ ln_g, size_t oG,
    const void* __restrict__ ln_b, size_t oBt,
    float* __restrict__ h_out, const void* __restrict__ lng)
{
    __shared__ float s_red[8];
    const int isbf = sniff_bf(lng);
    const int node = blockIdx.x, c = threadIdx.x;
    const int lane = c & 63, wv = c >> 6;

    float vch = part[((size_t)0 * NNTOT + node) * CH + c]
              + part[((size_t)1 * NNTOT + node) * CH + c]
              + part[((size_t)2 * NNTOT + node) * CH + c]
              + part[((size_t)3 * NNTOT + node) * CH + c]
              + ldm(bias, oB + c, isbf);

    float s1 = vch, s2 = vch * vch;
    s1 += __shfl_xor(s1, 32); s2 += __shfl_xor(s2, 32);
    s1 += __shfl_xor(s1, 16); s2 += __shfl_xor(s2, 16);
    s1 += __shfl_xor(s1, 8);  s2 += __shfl_xor(s2, 8);
    s1 += __shfl_xor(s1, 4);  s2 += __shfl_xor(s2, 4);
    s1 += __shfl_xor(s1, 2);  s2 += __shfl_xor(s2, 2);
    s1 += __shfl_xor(s1, 1);  s2 += __shfl_xor(s2, 1);
    if (lane == 0) { s_red[wv] = s1; s_red[4 + wv] = s2; }
    __syncthreads();
    const float S1 = s_red[0] + s_red[1] + s_red[2] + s_red[3];
    const float S2 = s_red[4] + s_red[5] + s_red[6] + s_red[7];
    const float mu  = S1 * (1.f / CH);
    const float var = S2 * (1.f / CH) - mu * mu;
    const float o = (vch - mu) * rsqrtf(var + LN_EPS) * ldm(ln_g, oG + c, isbf)
                  + ldm(ln_b, oBt + c, isbf);
    h_out[(size_t)node * CH + c] = o;
}

// ---------------------------------------------------------------- fused MLP
// grid (11, 2): block = 16 nodes. h_ln -> bf16 LDS; MLP1 (W1 chunked, m1 kept
// in LDS bf16); MLP2 (W2 chunked) + bias + residual -> out. All MFMA M=16.
__global__ __launch_bounds__(256) void k_mlp(
    const float* __restrict__ h_ln,
    const short* __restrict__ w1T, size_t oW1T,
    const void* __restrict__ b1, size_t oB1,
    const short* __restrict__ w2T, size_t oW2T,
    const void* __restrict__ b2, size_t oB2,
    const void* __restrict__ x_res, int israw,
    float* __restrict__ out, const void* __restrict__ lng)
{
    __shared__ short sA[16 * 264];      // h_ln bf16
    __shared__ short sM1[16 * M1PAD];   // m1 bf16 [16][512], stride 536 (2-way banks)
    __shared__ short sW[64 * 520];      // weight chunk stage (max 64x512, pad 8)
    const int isbf = sniff_bf(lng);
    const int r_bf = israw ? isbf : 0;
    const int g = blockIdx.y;
    const int d0 = blockIdx.x * 16;
    const int tid = threadIdx.x, lane = tid & 63, w = tid >> 6;
    const int m = lane & 15, kb = (lane >> 4) * 8, rq = (lane >> 4) * 4;
    const int w16 = w * 16;

    // stage A = h_ln rows -> bf16
    for (int i = tid; i < 16 * 64; i += 256) {
        const int si = i >> 6, c4 = (i & 63) * 4;
        const int d = d0 + si;
        const float4 v = (d < NNODES)
            ? *(const float4*)(h_ln + (size_t)(g * NNODES + d) * CH + c4)
            : make_float4(0.f, 0.f, 0.f, 0.f);
        short v4[4] = { f2bf(v.x), f2bf(v.y), f2bf(v.z), f2bf(v.w) };
        *(int2*)&sA[si * 264 + c4] = *(int2*)v4;
    }

    // ---- MLP1: 8 n-chunks of 64, K=256
    for (int nc = 0; nc < 8; nc++) {
        __syncthreads();   // also covers sA stage on first iter
        for (int i = tid; i < 64 * 32; i += 256) {
            const int r = i >> 5, k8 = (i & 31) * 8;
            *(int4*)&sW[r * 264 + k8] =
                *(const int4*)(w1T + oW1T + (size_t)(nc * 64 + r) * 256 + k8);
        }
        __syncthreads();
        float4v acc = {0.f, 0.f, 0.f, 0.f};
        #pragma unroll
        for (int kc = 0; kc < 8; kc++) {
            const short8v af = *(const short8v*)&sA[m * 264 + kc * 32 + kb];
            const short8v bfv = *(const short8v*)&sW[(w16 + m) * 264 + kc * 32 + kb];
            acc = __builtin_amdgcn_mfma_f32_16x16x32_bf16(af, bfv, acc, 0, 0, 0);
        }
        const int ng = nc * 64 + w16 + m;
        const float bv = ldm(b1, oB1 + ng, isbf);
        #pragma unroll
        for (int rr = 0; rr < 4; rr++)
            sM1[(rq + rr) * M1PAD + ng] = f2bf(fmaxf(acc[rr] + bv, 0.f));
    }

    // ---- MLP2: 4 n-chunks of 64, K=512
    for (int nc = 0; nc < 4; nc++) {
        __syncthreads();   // first iter: all sM1 writes visible; later: sW reuse
        for (int i = tid; i < 64 * 64; i += 256) {
            const int r = i >> 6, k8 = (i & 63) * 8;
            *(int4*)&sW[r * 520 + k8] =
                *(const int4*)(w2T + oW2T + (size_t)(nc * 64 + r) * 512 + k8);
        }
        __syncthreads();
        float4v acc = {0.f, 0.f, 0.f, 0.f};
        #pragma unroll
        for (int kc = 0; kc < 16; kc++) {
            const short8v af = *(const short8v*)&sM1[m * M1PAD + kc * 32 + kb];
            const short8v bfv = *(const short8v*)&sW[(w16 + m) * 520 + kc * 32 + kb];
            acc = __builtin_amdgcn_mfma_f32_16x16x32_bf16(af, bfv, acc, 0, 0, 0);
        }
        const int ng = nc * 64 + w16 + m;
        const float bv = ldm(b2, oB2 + ng, isbf);
        #pragma unroll
        for (int rr = 0; rr < 4; rr++) {
            const int d = d0 + rq + rr;
            if (d < NNODES) {
                const size_t ro = (size_t)(g * NNODES + d) * CH + ng;
                out[ro] = acc[rr] + bv + ldm(x_res, ro, r_bf);
            }
        }
    }
}

// ---------------------------------------------------------------- pool
__global__ __launch_bounds__(256) void k_pool(const float* __restrict__ x,
                                              void* __restrict__ out,
                                              const void* __restrict__ lng) {
    const int isbf = sniff_bf(lng);
    const int g = blockIdx.x, c = threadIdx.x;
    float s = 0.f;
    const float* p = x + (size_t)g * NNODES * CH + c;
    #pragma unroll 8
    for (int n = 0; n < NNODES; n++) s += p[(size_t)n * CH];
    const float v = s * (1.f / NNODES);
    if (isbf) ((bf16*)out)[g * CH + c] = __float2bfloat16(v);
    else      ((float*)out)[g * CH + c] = v;
}

// ---------------------------------------------------------------- launch
extern "C" void kernel_launch(void* const* d_in, const int* in_sizes, int n_in,
                              void* d_out, int out_size, void* d_ws, size_t ws_size,
                              hipStream_t stream)
{
    const void* x_in = d_in[0];
    const void* Wl   = d_in[1];
    const void* bl   = d_in[2];
    const void* Wr   = d_in[3];
    const void* br   = d_in[4];
    const void* att  = d_in[5];
    const void* bias = d_in[6];
    const void* lng  = d_in[7];
    const void* lnb  = d_in[8];
    const void* W1   = d_in[9];
    const void* b1   = d_in[10];
    const void* W2   = d_in[11];
    const void* b2   = d_in[12];

    float* ws     = (float*)d_ws;
    float* xl     = ws;                                      // 338*1024
    float* xr     = xl + (size_t)NNTOT * NH * CH;            // 338*1024
    float* alphaR = xr + (size_t)NNTOT * NH * CH;            // 2*4*169*176
    float* part   = alphaR + (size_t)2 * NH * NNODES * SPAD; // 4*338*256
    float* h_ln   = part + (size_t)NH * NNTOT * CH;          // 338*256
    float* xa     = h_ln + (size_t)NNTOT * CH;               // 338*256
    float* xb     = xa + (size_t)NNTOT * CH;                 // 338*256
    short* wlT    = (short*)(xb + (size_t)NNTOT * CH);       // 3*256*1024
    short* wrT    = wlT + (size_t)NL * CH * NH * CH;         // 3*256*1024
    short* w1T    = wrT + (size_t)NL * CH * NH * CH;         // 3*256*512
    short* w2T    = w1T + (size_t)NL * CH * 2 * CH;          // 3*512*256

    const size_t sB  = NH * CH;
    const size_t sA  = NH * CH;
    const size_t sC  = CH;
    const size_t sB1 = 2 * CH;
    const size_t sWT  = (size_t)CH * NH * CH;
    const size_t sW1T = (size_t)CH * 2 * CH;
    const size_t sW2T = (size_t)2 * CH * CH;

    k_wt<<<dim3(256, 1, 12), 256, 0, stream>>>(
        Wl, Wr, W1, W2, wlT, wrT, w1T, w2T, lng);

    const void* x_l[3] = { x_in, xa, xb };
    float*      x_o[3] = { xa, xb, xa };

    for (int l = 0; l < NL; l++) {
        const int israw = (l == 0);
        k_gemm_lr<<<dim3(6, 16, 2), 256, 0, stream>>>(
            x_l[l], israw, wlT, wrT, (size_t)l * sWT,
            bl, br, (size_t)l * sB, xl, xr, lng);
        k_logits_sm<<<dim3(43, NH, 2), 256, 0, stream>>>(
            xl, xr, att, (size_t)l * sA, alphaR, lng);
        k_agg<<<dim3(6, 4, 8), 256, 0, stream>>>(alphaR, xl, part);
        k_ln<<<dim3(NNTOT), 256, 0, stream>>>(
            part, bias, (size_t)l * sC, lng, (size_t)l * sC, lnb, (size_t)l * sC,
            h_ln, lng);
        k_mlp<<<dim3(11, 2), 256, 0, stream>>>(
            h_ln, w1T, (size_t)l * sW1T, b1, (size_t)l * sB1,
            w2T, (size_t)l * sW2T, b2, (size_t)l * sC,
            x_l[l], israw, x_o[l], lng);
    }

    k_pool<<<dim3(2), 256, 0, stream>>>(xa, d_out, lng);
}

// Round 12
// 388.710 us; speedup vs baseline: 1.0168x; 1.0168x over previous
//
#include <hip/hip_runtime.h>
#include <hip/hip_bf16.h>

typedef __hip_bfloat16 bf16;
typedef __attribute__((ext_vector_type(8))) short short8v;
typedef __attribute__((ext_vector_type(4))) float float4v;

#define NNODES 169
#define NNTOT  338
#define CH     256
#define NH     4
#define NL     3
#define SPAD   176
#define TPAD   177
#define LN_EPS 1e-5f

__device__ __forceinline__ float b2f(bf16 v) { return __bfloat162float(v); }
__device__ __forceinline__ float lrelu(float v) { return fmaxf(v, 0.2f * v); }
__device__ __forceinline__ float ldm(const void* p, size_t i, int isbf) {
    return isbf ? b2f(((const bf16*)p)[i]) : ((const float*)p)[i];
}
__device__ __forceinline__ short f2bf(float f) {   // RNE fp32 -> bf16 bits
    union { float f; unsigned u; } x; x.f = f;
    return (short)((x.u + 0x7FFFu + ((x.u >> 16) & 1u)) >> 16);
}
__device__ __forceinline__ int sniff_bf(const void* lng) {
    return ((((const unsigned*)lng)[0] & 0xFFFFu) == 0x3F80u) ? 1 : 0;
}

// ---------------------------------------------------------------- weight transpose
// WT[n][k] bf16 for all 4 weight families x 3 layers. grid (256,1,12).
__global__ __launch_bounds__(256) void k_wt(
    const void* __restrict__ Wl, const void* __restrict__ Wr,
    const void* __restrict__ W1, const void* __restrict__ W2,
    short* __restrict__ wlT, short* __restrict__ wrT,
    short* __restrict__ w1T, short* __restrict__ w2T,
    const void* __restrict__ lng)
{
    __shared__ float s_t[32][33];
    const int isbf = sniff_bf(lng);
    const int z = blockIdx.z, mat = z & 3, l = z >> 2;
    const void* src; short* dst; int K, N;
    if      (mat == 0) { src = Wl; dst = wlT; K = CH;     N = NH * CH; }
    else if (mat == 1) { src = Wr; dst = wrT; K = CH;     N = NH * CH; }
    else if (mat == 2) { src = W1; dst = w1T; K = CH;     N = 2 * CH;  }
    else               { src = W2; dst = w2T; K = 2 * CH; N = CH;      }
    const int tiles = (K >> 5) * (N >> 5);
    if ((int)blockIdx.x >= tiles) return;
    const int tn = blockIdx.x % (N >> 5), tk = blockIdx.x / (N >> 5);
    const int k0 = tk * 32, n0 = tn * 32;
    const size_t lKN = (size_t)l * K * N;
    const int tx = threadIdx.x & 31, ty = threadIdx.x >> 5;

    for (int r = ty; r < 32; r += 8)
        s_t[r][tx] = ldm(src, lKN + (size_t)(k0 + r) * N + n0 + tx, isbf);
    __syncthreads();
    for (int r = ty; r < 32; r += 8)
        dst[lKN + (size_t)(n0 + r) * K + k0 + tx] = f2bf(s_t[tx][r]);
}

// ---------------------------------------------------------------- MFMA GEMM core
// 64x64 tile, full-K LDS stage (ONE barrier), then KK/32 uninterrupted MFMA
// chunks. A fp32 (or raw bf16) -> bf16 staged; WT[n][k] bf16 pre-transposed.
template<int KK, int ACT, int RES>
__device__ __forceinline__ void mfma_gemm(
    short* __restrict__ sA, short* __restrict__ sBT,
    const void* __restrict__ Av, int a_bf,
    const short* __restrict__ WT,
    const void* __restrict__ bv_, size_t oB, int isbf,
    const void* __restrict__ x_res, int r_bf,
    float* __restrict__ out,
    int M, int N, int row0, int col0)
{
    const int STR = KK + 8;                    // shorts; 2-way banks (free)
    const int tid = threadIdx.x, lane = tid & 63, w = tid >> 6;
    const int r = tid >> 2, q = tid & 3;       // stage: row, k-quarter
    const int kseg = KK / 4, kb0 = q * kseg;
    const int m = lane & 15, kb = (lane >> 4) * 8;
    const int w16 = w * 16;

    {   // ---- stage A (convert to bf16) and B, one pass
        const int gr = row0 + r;
        const int ok = (gr < M);
        if (a_bf) {
            const bf16* ap = (const bf16*)Av + (size_t)gr * KK + kb0;
            #pragma unroll
            for (int j = 0; j < kseg; j += 8) {
                int4 v = ok ? *(const int4*)(ap + j) : make_int4(0, 0, 0, 0);
                *(int4*)&sA[r * STR + kb0 + j] = v;
            }
        } else {
            const float* ap = (const float*)Av + (size_t)gr * KK + kb0;
            #pragma unroll
            for (int j = 0; j < kseg; j += 8) {
                short v8[8];
                if (ok) {
                    const float4 f0 = *(const float4*)(ap + j);
                    const float4 f1 = *(const float4*)(ap + j + 4);
                    v8[0] = f2bf(f0.x); v8[1] = f2bf(f0.y);
                    v8[2] = f2bf(f0.z); v8[3] = f2bf(f0.w);
                    v8[4] = f2bf(f1.x); v8[5] = f2bf(f1.y);
                    v8[6] = f2bf(f1.z); v8[7] = f2bf(f1.w);
                } else {
                    #pragma unroll
                    for (int u = 0; u < 8; u++) v8[u] = 0;
                }
                *(int4*)&sA[r * STR + kb0 + j] = *(int4*)v8;
            }
        }
        const short* bp = WT + (size_t)(col0 + r) * KK + kb0;
        #pragma unroll
        for (int j = 0; j < kseg; j += 8)
            *(int4*)&sBT[r * STR + kb0 + j] = *(const int4*)(bp + j);
    }
    __syncthreads();

    float4v acc[4];
    #pragma unroll
    for (int t = 0; t < 4; t++) acc[t] = (float4v){0.f, 0.f, 0.f, 0.f};

    #pragma unroll
    for (int kc = 0; kc < KK / 32; kc++) {
        const short8v af = *(const short8v*)&sA[(w16 + m) * STR + kc * 32 + kb];
        #pragma unroll
        for (int t = 0; t < 4; t++) {
            const short8v bfv = *(const short8v*)&sBT[(t * 16 + m) * STR + kc * 32 + kb];
            acc[t] = __builtin_amdgcn_mfma_f32_16x16x32_bf16(af, bfv, acc[t], 0, 0, 0);
        }
    }

    const int rq = (lane >> 4) * 4;
    #pragma unroll
    for (int t = 0; t < 4; t++) {
        const int col = col0 + t * 16 + m;
        const float bias_v = ldm(bv_, oB + col, isbf);
        #pragma unroll
        for (int rr = 0; rr < 4; rr++) {
            const int gr = row0 + w16 + rq + rr;
            if (gr >= M) continue;
            float v = acc[t][rr] + bias_v;
            if (ACT) v = fmaxf(v, 0.f);
            if (RES) v += ldm(x_res, (size_t)gr * N + col, r_bf);
            out[(size_t)gr * N + col] = v;
        }
    }
}

// grid (6,16,2): z=0 -> xl, z=1 -> xr.  K=256, N=1024.
__global__ __launch_bounds__(256) void k_gemm_lr(
    const void* __restrict__ Av, int israw,
    const short* __restrict__ wlT, const short* __restrict__ wrT, size_t oWT,
    const void* __restrict__ bl, const void* __restrict__ br, size_t oB,
    float* __restrict__ xl, float* __restrict__ xr,
    const void* __restrict__ lng)
{
    __shared__ short sA[64 * 264];
    __shared__ short sBT[64 * 264];
    const int isbf = sniff_bf(lng);
    const int a_bf = israw ? isbf : 0;
    const int row0 = blockIdx.x * 64, col0 = blockIdx.y * 64;
    if (blockIdx.z == 0)
        mfma_gemm<256,0,0>(sA, sBT, Av, a_bf, wlT + oWT, bl, oB, isbf,
                           nullptr, 0, xl, NNTOT, NH * CH, row0, col0);
    else
        mfma_gemm<256,0,0>(sA, sBT, Av, a_bf, wrT + oWT, br, oB, isbf,
                           nullptr, 0, xr, NNTOT, NH * CH, row0, col0);
}

// ---------------------------------------------------------------- logits + softmax
// grid (22, NH, 2): block owns 8 targets for one (g,h). xl h-slice staged to
// LDS transposed in 4 chunks of 64ch x 176src; channel loop all-LDS; softmax
// fused (waves handle rows wv and wv+4). alphaR rows carry 0.25/z.
__global__ __launch_bounds__(256) void k_logits_sm(
    const float* __restrict__ xl, const float* __restrict__ xr,
    const void* __restrict__ att, size_t oA,
    float* __restrict__ alphaR, const void* __restrict__ lng)
{
    __shared__ float s_att[CH];
    __shared__ float s_xr[8 * CH];
    __shared__ float s_tile[64 * TPAD];
    __shared__ float s_log[8 * SPAD];
    const int isbf = sniff_bf(lng);
    const int g = blockIdx.z, h = blockIdx.y, d0 = blockIdx.x * 8;
    const int tid = threadIdx.x, lane = tid & 63, wv = tid >> 6;

    s_att[tid] = ldm(att, oA + h * CH + tid, isbf);
    #pragma unroll
    for (int i = 0; i < 8; i++) {
        const int d = d0 + i;
        s_xr[i * CH + tid] = (d < NNODES)
            ? xr[(size_t)(g * NNODES + d) * (NH * CH) + h * CH + tid] : 0.f;
    }

    float l[8] = {0.f, 0.f, 0.f, 0.f, 0.f, 0.f, 0.f, 0.f};
    const int s = tid;
    for (int ch = 0; ch < 4; ch++) {
        __syncthreads();
        for (int i = tid; i < SPAD * 16; i += 256) {
            const int si = i >> 4, c4 = (i & 15) * 4;
            const float4 v = (si < NNODES)
                ? *(const float4*)(xl + (size_t)(g * NNODES + si) * (NH * CH)
                                   + h * CH + ch * 64 + c4)
                : make_float4(0.f, 0.f, 0.f, 0.f);
            s_tile[(c4 + 0) * TPAD + si] = v.x;
            s_tile[(c4 + 1) * TPAD + si] = v.y;
            s_tile[(c4 + 2) * TPAD + si] = v.z;
            s_tile[(c4 + 3) * TPAD + si] = v.w;
        }
        __syncthreads();
        if (s < NNODES) {
            const int cb = ch * 64;
            #pragma unroll 4
            for (int c = 0; c < 64; c++) {
                const float v = s_tile[c * TPAD + s];
                const float a = s_att[cb + c];
                #pragma unroll
                for (int i = 0; i < 8; i++)
                    l[i] += a * lrelu(v + s_xr[i * CH + cb + c]);
            }
        }
    }
    if (s < NNODES) {
        #pragma unroll
        for (int i = 0; i < 8; i++) s_log[i * SPAD + s] = l[i];
    }
    __syncthreads();

    #pragma unroll
    for (int p = 0; p < 2; p++) {   // wave wv reduces rows wv and wv+4
        const int ri = p * 4 + wv;
        const int d = d0 + ri;
        const float* row = s_log + ri * SPAD;
        const int s0 = lane, s1 = lane + 64, s2 = lane + 128;
        const float v0 = (s0 < NNODES && s0 != d) ? row[s0] : -1e30f;
        const float v1 = (s1 < NNODES && s1 != d) ? row[s1] : -1e30f;
        const float v2 = (s2 < NNODES && s2 != d) ? row[s2] : -1e30f;
        float mx = fmaxf(v0, fmaxf(v1, v2));
        mx = fmaxf(mx, __shfl_xor(mx, 32)); mx = fmaxf(mx, __shfl_xor(mx, 16));
        mx = fmaxf(mx, __shfl_xor(mx, 8));  mx = fmaxf(mx, __shfl_xor(mx, 4));
        mx = fmaxf(mx, __shfl_xor(mx, 2));  mx = fmaxf(mx, __shfl_xor(mx, 1));
        const float e0 = expf(v0 - mx), e1 = expf(v1 - mx), e2 = expf(v2 - mx);
        float z = e0 + e1 + e2;
        z += __shfl_xor(z, 32); z += __shfl_xor(z, 16); z += __shfl_xor(z, 8);
        z += __shfl_xor(z, 4);  z += __shfl_xor(z, 2);  z += __shfl_xor(z, 1);
        const float sc = 0.25f / (z + 1e-16f);     // head-mean folded in
        if (d < NNODES) {
            float* arow = alphaR + ((size_t)(g * NH + h) * NNODES + d) * SPAD;
            if (s0 < NNODES) arow[s0] = e0 * sc;
            if (s1 < NNODES) arow[s1] = e1 * sc;
            if (s2 < NNODES) arow[s2] = e2 * sc;
        }
    }
}

// ---------------------------------------------------------------- aggregate as GEMM
// part[h][g*169+d][c] = sum_s alpha[d,s] * xl[s, h*256+c], per (g,h).
// grid (6 d-tiles of 32, 4 c-tiles of 64, 8 gh). K = sources, BK=32.
__global__ __launch_bounds__(256) void k_agg(
    const float* __restrict__ alphaR, const float* __restrict__ xl,
    float* __restrict__ part)
{
    __shared__ float s_a[32 * 33];
    __shared__ float s_x[32 * 64];
    const int gh = blockIdx.z, g = gh >> 2, h = gh & 3;
    const int d0 = blockIdx.x * 32, c0 = blockIdx.y * 64;
    const int tid = threadIdx.x;
    const int dr = (tid >> 4) * 2, cq = (tid & 15) * 4;
    const int sr = tid >> 3, sc4 = (tid & 7) * 4;
    const int xc8 = (tid & 7) * 8;

    float acc[2][4] = {{0.f,0.f,0.f,0.f},{0.f,0.f,0.f,0.f}};

    for (int s0 = 0; s0 < NNODES; s0 += 32) {
        __syncthreads();
        {
            const int d = d0 + sr;
            const float* ap = alphaR + ((size_t)gh * NNODES + d) * SPAD + s0 + sc4;
            const int ok = (d < NNODES);
            s_a[sr * 33 + sc4 + 0] = (ok && s0 + sc4 + 0 < NNODES) ? ap[0] : 0.f;
            s_a[sr * 33 + sc4 + 1] = (ok && s0 + sc4 + 1 < NNODES) ? ap[1] : 0.f;
            s_a[sr * 33 + sc4 + 2] = (ok && s0 + sc4 + 2 < NNODES) ? ap[2] : 0.f;
            s_a[sr * 33 + sc4 + 3] = (ok && s0 + sc4 + 3 < NNODES) ? ap[3] : 0.f;
        }
        {
            const int sg = s0 + sr;
            if (sg < NNODES) {
                const float* xp = xl + (size_t)(g * NNODES + sg) * (NH * CH) + h * CH + c0 + xc8;
                *(float4*)&s_x[sr * 64 + xc8]     = *(const float4*)(xp);
                *(float4*)&s_x[sr * 64 + xc8 + 4] = *(const float4*)(xp + 4);
            } else {
                #pragma unroll
                for (int j = 0; j < 8; j++) s_x[sr * 64 + xc8 + j] = 0.f;
            }
        }
        __syncthreads();
        #pragma unroll
        for (int k = 0; k < 32; k++) {
            const float a0 = s_a[(dr + 0) * 33 + k];
            const float a1 = s_a[(dr + 1) * 33 + k];
            const float4 xv = *(const float4*)&s_x[k * 64 + cq];
            acc[0][0] += a0 * xv.x; acc[0][1] += a0 * xv.y;
            acc[0][2] += a0 * xv.z; acc[0][3] += a0 * xv.w;
            acc[1][0] += a1 * xv.x; acc[1][1] += a1 * xv.y;
            acc[1][2] += a1 * xv.z; acc[1][3] += a1 * xv.w;
        }
    }
    #pragma unroll
    for (int i = 0; i < 2; i++) {
        const int d = d0 + dr + i;
        if (d >= NNODES) continue;
        float4 v;
        v.x = acc[i][0]; v.y = acc[i][1]; v.z = acc[i][2]; v.w = acc[i][3];
        *(float4*)(part + ((size_t)h * NNTOT + g * NNODES + d) * CH + c0 + cq) = v;
    }
}

// ---------------------------------------------------------------- LN + MLP1
// grid (6, 8): 64 nodes x 64 W1-cols per block. Head-sum+bias -> LDS fp32,
// row mean/var in-block, normalize -> bf16 A, then MFMA with staged W1.
__global__ __launch_bounds__(256) void k_lnmlp1(
    const float* __restrict__ part,
    const void* __restrict__ bias, size_t oB,
    const void* __restrict__ ln_g, size_t oG,
    const void* __restrict__ ln_b, size_t oBt,
    const short* __restrict__ w1T, size_t oW1T,
    const void* __restrict__ b1, size_t oB1,
    float* __restrict__ m1, const void* __restrict__ lng)
{
    __shared__ float s_row[64 * 260];    // 66.6 KB (stride 260 -> 2-way banks)
    __shared__ short sA[64 * 264];       // 33.8 KB
    __shared__ short sW[64 * 264];       // 33.8 KB
    __shared__ float s_red[64 * 8];      // 2 KB
    const int isbf = sniff_bf(lng);
    const int row0 = blockIdx.x * 64, col0 = blockIdx.y * 64;
    const int tid = threadIdx.x, lane = tid & 63, w = tid >> 6;
    const int m = lane & 15, kb = (lane >> 4) * 8, rq = (lane >> 4) * 4;
    const int w16 = w * 16;
    const int r = tid >> 2, q = tid & 3, cb = q * 64;

    // stage W1 columns (no dependency on s_row)
    for (int i = tid; i < 64 * 32; i += 256) {
        const int rr = i >> 5, k8 = (i & 31) * 8;
        *(int4*)&sW[rr * 264 + k8] =
            *(const int4*)(w1T + oW1T + (size_t)(col0 + rr) * 256 + k8);
    }

    // head-sum + bias into s_row; per-thread partial LN sums
    {
        const int gr = row0 + r;
        float s1 = 0.f, s2 = 0.f;
        if (gr < NNTOT) {
            for (int c = cb; c < cb + 64; c += 4) {
                const float4 v0 = *(const float4*)(part + ((size_t)0 * NNTOT + gr) * CH + c);
                const float4 v1 = *(const float4*)(part + ((size_t)1 * NNTOT + gr) * CH + c);
                const float4 v2 = *(const float4*)(part + ((size_t)2 * NNTOT + gr) * CH + c);
                const float4 v3 = *(const float4*)(part + ((size_t)3 * NNTOT + gr) * CH + c);
                float4 o;
                o.x = v0.x + v1.x + v2.x + v3.x + ldm(bias, oB + c + 0, isbf);
                o.y = v0.y + v1.y + v2.y + v3.y + ldm(bias, oB + c + 1, isbf);
                o.z = v0.z + v1.z + v2.z + v3.z + ldm(bias, oB + c + 2, isbf);
                o.w = v0.w + v1.w + v2.w + v3.w + ldm(bias, oB + c + 3, isbf);
                *(float4*)&s_row[r * 260 + c] = o;
                s1 += o.x + o.y + o.z + o.w;
                s2 += o.x * o.x + o.y * o.y + o.z * o.z + o.w * o.w;
            }
        } else {
            for (int c = cb; c < cb + 64; c += 4)
                *(float4*)&s_row[r * 260 + c] = make_float4(0.f, 0.f, 0.f, 0.f);
        }
        s_red[r * 8 + q * 2 + 0] = s1;
        s_red[r * 8 + q * 2 + 1] = s2;
    }
    __syncthreads();
    if (tid < 64) {
        const float S1 = s_red[tid * 8 + 0] + s_red[tid * 8 + 2]
                       + s_red[tid * 8 + 4] + s_red[tid * 8 + 6];
        const float S2 = s_red[tid * 8 + 1] + s_red[tid * 8 + 3]
                       + s_red[tid * 8 + 5] + s_red[tid * 8 + 7];
        const float mu  = S1 * (1.f / CH);
        const float var = S2 * (1.f / CH) - mu * mu;
        s_red[tid * 8 + 0] = mu;
        s_red[tid * 8 + 1] = rsqrtf(var + LN_EPS);
    }
    __syncthreads();
    {   // normalize -> bf16 A
        const float mu = s_red[r * 8 + 0], rs = s_red[r * 8 + 1];
        for (int c = cb; c < cb + 64; c += 4) {
            const float4 v = *(const float4*)&s_row[r * 260 + c];
            short v4[4];
            v4[0] = f2bf((v.x - mu) * rs * ldm(ln_g, oG + c + 0, isbf) + ldm(ln_b, oBt + c + 0, isbf));
            v4[1] = f2bf((v.y - mu) * rs * ldm(ln_g, oG + c + 1, isbf) + ldm(ln_b, oBt + c + 1, isbf));
            v4[2] = f2bf((v.z - mu) * rs * ldm(ln_g, oG + c + 2, isbf) + ldm(ln_b, oBt + c + 2, isbf));
            v4[3] = f2bf((v.w - mu) * rs * ldm(ln_g, oG + c + 3, isbf) + ldm(ln_b, oBt + c + 3, isbf));
            *(int2*)&sA[r * 264 + c] = *(int2*)v4;
        }
    }
    __syncthreads();

    float4v acc[4];
    #pragma unroll
    for (int t = 0; t < 4; t++) acc[t] = (float4v){0.f, 0.f, 0.f, 0.f};
    #pragma unroll
    for (int kc = 0; kc < 8; kc++) {
        const short8v af = *(const short8v*)&sA[(w16 + m) * 264 + kc * 32 + kb];
        #pragma unroll
        for (int t = 0; t < 4; t++) {
            const short8v bfv = *(const short8v*)&sW[(t * 16 + m) * 264 + kc * 32 + kb];
            acc[t] = __builtin_amdgcn_mfma_f32_16x16x32_bf16(af, bfv, acc[t], 0, 0, 0);
        }
    }
    #pragma unroll
    for (int t = 0; t < 4; t++) {
        const int col = col0 + t * 16 + m;
        const float bv = ldm(b1, oB1 + col, isbf);
        #pragma unroll
        for (int rr = 0; rr < 4; rr++) {
            const int gr = row0 + w16 + rq + rr;
            if (gr >= NNTOT) continue;
            m1[(size_t)gr * (2 * CH) + col] = fmaxf(acc[t][rr] + bv, 0.f);
        }
    }
}

// grid (6,4): x_next = x_res + m1 @ W2 + b2. K=512, N=256.
__global__ __launch_bounds__(256) void k_mlp2(
    const float* __restrict__ A, const short* __restrict__ w2T, size_t oWT,
    const void* __restrict__ b, size_t oB,
    const void* __restrict__ x_res, int israw,
    float* __restrict__ out, const void* __restrict__ lng)
{
    __shared__ short sA[64 * 520];
    __shared__ short sBT[64 * 520];
    const int isbf = sniff_bf(lng);
    const int r_bf = israw ? isbf : 0;
    mfma_gemm<512,0,1>(sA, sBT, A, 0, w2T + oWT, b, oB, isbf, x_res, r_bf,
                       out, NNTOT, CH, blockIdx.x * 64, blockIdx.y * 64);
}

// ---------------------------------------------------------------- pool
__global__ __launch_bounds__(256) void k_pool(const float* __restrict__ x,
                                              void* __restrict__ out,
                                              const void* __restrict__ lng) {
    const int isbf = sniff_bf(lng);
    const int g = blockIdx.x, c = threadIdx.x;
    float s = 0.f;
    const float* p = x + (size_t)g * NNODES * CH + c;
    #pragma unroll 8
    for (int n = 0; n < NNODES; n++) s += p[(size_t)n * CH];
    const float v = s * (1.f / NNODES);
    if (isbf) ((bf16*)out)[g * CH + c] = __float2bfloat16(v);
    else      ((float*)out)[g * CH + c] = v;
}

// ---------------------------------------------------------------- launch
extern "C" void kernel_launch(void* const* d_in, const int* in_sizes, int n_in,
                              void* d_out, int out_size, void* d_ws, size_t ws_size,
                              hipStream_t stream)
{
    const void* x_in = d_in[0];
    const void* Wl   = d_in[1];
    const void* bl   = d_in[2];
    const void* Wr   = d_in[3];
    const void* br   = d_in[4];
    const void* att  = d_in[5];
    const void* bias = d_in[6];
    const void* lng  = d_in[7];
    const void* lnb  = d_in[8];
    const void* W1   = d_in[9];
    const void* b1   = d_in[10];
    const void* W2   = d_in[11];
    const void* b2   = d_in[12];

    float* ws     = (float*)d_ws;
    float* xl     = ws;                                      // 338*1024
    float* xr     = xl + (size_t)NNTOT * NH * CH;            // 338*1024
    float* alphaR = xr + (size_t)NNTOT * NH * CH;            // 2*4*169*176
    float* part   = alphaR + (size_t)2 * NH * NNODES * SPAD; // 4*338*256
    float* m1     = part + (size_t)NH * NNTOT * CH;          // 338*512
    float* xa     = m1 + (size_t)NNTOT * 2 * CH;             // 338*256
    float* xb     = xa + (size_t)NNTOT * CH;                 // 338*256
    short* wlT    = (short*)(xb + (size_t)NNTOT * CH);       // 3*256*1024
    short* wrT    = wlT + (size_t)NL * CH * NH * CH;         // 3*256*1024
    short* w1T    = wrT + (size_t)NL * CH * NH * CH;         // 3*256*512
    short* w2T    = w1T + (size_t)NL * CH * 2 * CH;          // 3*512*256

    const size_t sB  = NH * CH;
    const size_t sA_ = NH * CH;
    const size_t sC  = CH;
    const size_t sB1 = 2 * CH;
    const size_t sWT  = (size_t)CH * NH * CH;
    const size_t sW1T = (size_t)CH * 2 * CH;
    const size_t sW2T = (size_t)2 * CH * CH;

    k_wt<<<dim3(256, 1, 12), 256, 0, stream>>>(
        Wl, Wr, W1, W2, wlT, wrT, w1T, w2T, lng);

    const void* x_l[3] = { x_in, xa, xb };
    float*      x_o[3] = { xa, xb, xa };

    for (int l = 0; l < NL; l++) {
        const int israw = (l == 0);
        k_gemm_lr<<<dim3(6, 16, 2), 256, 0, stream>>>(
            x_l[l], israw, wlT, wrT, (size_t)l * sWT,
            bl, br, (size_t)l * sB, xl, xr, lng);
        k_logits_sm<<<dim3(22, NH, 2), 256, 0, stream>>>(
            xl, xr, att, (size_t)l * sA_, alphaR, lng);
        k_agg<<<dim3(6, 4, 8), 256, 0, stream>>>(alphaR, xl, part);
        k_lnmlp1<<<dim3(6, 8), 256, 0, stream>>>(
            part, bias, (size_t)l * sC, lng, (size_t)l * sC, lnb, (size_t)l * sC,
            w1T, (size_t)l * sW1T, b1, (size_t)l * sB1, m1, lng);
        k_mlp2<<<dim3(6, 4), 256, 0, stream>>>(
            m1, w2T, (size_t)l * sW2T, b2, (size_t)l * sC,
            x_l[l], israw, x_o[l], lng);
    }

    k_pool<<<dim3(2), 256, 0, stream>>>(xa, d_out, lng);
}